// Round 15
// baseline (183.833 us; speedup 1.0000x reference)
//
#include <hip/hip_runtime.h>
#include <stdint.h>

/* AdditiveAttention (B=4, Q=256, K=1024, D=512, H=256)
 * out[b,i,v] = sum_j softmax_j(sum_h tanh(q[b,i,h]+k[b,j,h])*wv[h]) * values[b,j,v],
 * masked to j < valid_lens[b].  OUTPUT IS FLOAT32 (R20 finding).
 *
 * R35: three instruction-count fixes.
 * (a) attn_s el staging: R14's stride-4 writes were 8-way bank conflicts
 *     (SQ_LDS_BANK_CONFLICT 3.38M). Pad to stride-5 (odd) -> conflict-free.
 * (b) proj: 2 h-tiles per wave (640 blocks, 2 WT float4 + 4 broadcast LDS
 *     + 32 FMA per d4) -> broadcast-LDS instrs halved (2.6M -> 1.3M; R13
 *     showed these are ~12cyc). trs transpose padded to stride-17 (was a
 *     16-way write conflict).
 * (c) pv: 8 q-rows/block (grid 1024, 2 Eg float4 streams, 16KB part) ->
 *     values L2 traffic halved (512 -> 256 MB).
 * attn_s FF_PAIRK math and structure = R14-verified; Eg/Sg layout same. */

#define NB 4
#define NQ 256
#define NK 1024
#define ND 512
#define NH 256
#define QROWS 4
#define PJR 16

#define C2L2E 2.8853900817779268f   /* 2*log2(e) */
#define L2E   1.4426950408889634f   /* log2(e)   */

typedef float v2f __attribute__((ext_vector_type(2)));

/* 8-class valid_lens decode: {i32,i64,f32,f64,i16,f16,bf16,fallback}. */
__device__ void ff_vldec(const int* p, int* v) {
  bool ok = true;
  for (int i = 0; i < 4; ++i) { int x = p[i]; if (x < 1 || x > NK) ok = false; }
  if (ok) { for (int i = 0; i < 4; ++i) v[i] = p[i]; return; }
  ok = true;
  for (int i = 0; i < 4; ++i) {
    if (p[2 * i + 1] != 0) ok = false;
    int x = p[2 * i]; if (x < 1 || x > NK) ok = false;
  }
  if (ok) { for (int i = 0; i < 4; ++i) v[i] = p[2 * i]; return; }
  ok = true;
  for (int i = 0; i < 4; ++i) {
    union { int i; float f; } u; u.i = p[i];
    if (!(u.f >= 1.0f && u.f <= 1024.0f && u.f == floorf(u.f))) ok = false;
  }
  if (ok) {
    for (int i = 0; i < 4; ++i) { union { int i; float f; } u; u.i = p[i]; v[i] = (int)u.f; }
    return;
  }
  ok = true;
  for (int i = 0; i < 4; ++i) {
    union { long long l; double d; } u;
    u.l = ((long long)p[2 * i + 1] << 32) | (unsigned int)p[2 * i];
    if (!(u.d >= 1.0 && u.d <= 1024.0 && u.d == floor(u.d))) ok = false;
  }
  if (ok) {
    for (int i = 0; i < 4; ++i) {
      union { long long l; double d; } u;
      u.l = ((long long)p[2 * i + 1] << 32) | (unsigned int)p[2 * i];
      v[i] = (int)u.d;
    }
    return;
  }
  const uint16_t* hh = (const uint16_t*)p;
  const short*    s  = (const short*)p;
  ok = true;
  for (int i = 0; i < 4; ++i) { int x = s[i]; if (x < 1 || x > NK) ok = false; }
  if (ok) { for (int i = 0; i < 4; ++i) v[i] = s[i]; return; }
  ok = true;
  for (int i = 0; i < 4; ++i) {
    union { uint16_t u; _Float16 h; } u; u.u = hh[i];
    float f = (float)u.h;
    if (!(f >= 1.0f && f <= 1024.0f && f == floorf(f))) ok = false;
  }
  if (ok) {
    for (int i = 0; i < 4; ++i) {
      union { uint16_t u; _Float16 h; } u; u.u = hh[i];
      v[i] = (int)(float)u.h;
    }
    return;
  }
  ok = true;
  for (int i = 0; i < 4; ++i) {
    union { uint32_t u; float f; } u; u.u = ((uint32_t)hh[i]) << 16;
    if (!(u.f >= 1.0f && u.f <= 1028.0f)) ok = false;
  }
  if (ok) {
    for (int i = 0; i < 4; ++i) {
      union { uint32_t u; float f; } u; u.u = ((uint32_t)hh[i]) << 16;
      int x = (int)(u.f + 0.5f); if (x > NK) x = NK; v[i] = x;
    }
    return;
  }
  for (int i = 0; i < 4; ++i) v[i] = NK;  /* fail-safe: unmasked */
}

/* Transpose W[h][d] -> WT float4 #(d4*NH+h) = C2L2E * W[h][4d4..4d4+3]. */
__global__ __launch_bounds__(256) void ff_wt(
    const float* __restrict__ Wq, const float* __restrict__ Wk,
    float* __restrict__ WTq, float* __restrict__ WTk)
{
  const int idx = blockIdx.x * 256 + threadIdx.x;   /* 0..32767 */
  const int d4 = idx & 127, h = idx >> 7;
  const float* src = blockIdx.y ? Wk : Wq;
  float*       dst = blockIdx.y ? WTk : WTq;
  float4 w = *(const float4*)(src + (size_t)h * ND + d4 * 4);
  w.x *= C2L2E; w.y *= C2L2E; w.z *= C2L2E; w.w *= C2L2E;
  *(float4*)(dst + ((size_t)d4 * NH + h) * 4) = w;
}

/* Projection: grid = 320 row-groups x 2 h-halves = 640 blocks, 256 thr.
 * Wave rw: rows 4rw..4rw+3; lane L; 2 h-tiles (hh*128 + {0,64} + L).
 * Per d4: 2 WT float4 (coalesced) + 4 broadcast LDS b128 + 32 FMA.
 * Outputs Aq=2^{q'} (qp [r][h]) / Ak=2^{k'} interleaved kp4[b][j][k]
 * via stride-17-padded LDS transpose. */
__global__ __launch_bounds__(256) void ff_proj(
    const float* __restrict__ q_in, const float* __restrict__ k_in,
    const float* __restrict__ WTq, const float* __restrict__ WTk,
    float* __restrict__ qp, float* __restrict__ kp)
{
  __shared__ float xs[PJR * ND];                 /* 32 KB */
  const int t  = threadIdx.x;
  const int rg = blockIdx.x >> 1;                /* 0..319 */
  const int hh = blockIdx.x & 1;                 /* h half 0..1 */
  const int gr0 = rg * PJR;
  const bool isq = gr0 < NB * NQ;
  const float* xin = isq ? (q_in + (size_t)gr0 * ND)
                         : (k_in + (size_t)(gr0 - NB * NQ) * ND);
  const float4* wt4 = (const float4*)(isq ? WTq : WTk);

  #pragma unroll
  for (int i = 0; i < 8; ++i)
    ((float4*)xs)[t + 256 * i] = ((const float4*)xin)[t + 256 * i];
  __syncthreads();

  const int L  = t & 63;
  const int rw = t >> 6;
  float ac0[4], ac1[4];                          /* [tile][row] */
  #pragma unroll
  for (int r = 0; r < 4; ++r) { ac0[r] = 0.f; ac1[r] = 0.f; }
  const float4* xr = (const float4*)xs + (size_t)(4 * rw) * 128;
  const int hbase = hh * 128 + L;

  #pragma unroll 4
  for (int d4 = 0; d4 < ND / 4; ++d4) {
    float4 w0 = wt4[(size_t)d4 * NH + hbase];
    float4 w1 = wt4[(size_t)d4 * NH + hbase + 64];
    float4 x0 = xr[d4];
    float4 x1 = xr[128 + d4];
    float4 x2 = xr[256 + d4];
    float4 x3 = xr[384 + d4];
    ac0[0] += w0.x*x0.x + w0.y*x0.y + w0.z*x0.z + w0.w*x0.w;
    ac0[1] += w0.x*x1.x + w0.y*x1.y + w0.z*x1.z + w0.w*x1.w;
    ac0[2] += w0.x*x2.x + w0.y*x2.y + w0.z*x2.z + w0.w*x2.w;
    ac0[3] += w0.x*x3.x + w0.y*x3.y + w0.z*x3.z + w0.w*x3.w;
    ac1[0] += w1.x*x0.x + w1.y*x0.y + w1.z*x0.z + w1.w*x0.w;
    ac1[1] += w1.x*x1.x + w1.y*x1.y + w1.z*x1.z + w1.w*x1.w;
    ac1[2] += w1.x*x2.x + w1.y*x2.y + w1.z*x2.z + w1.w*x2.w;
    ac1[3] += w1.x*x3.x + w1.y*x3.y + w1.z*x3.z + w1.w*x3.w;
  }
  #pragma unroll
  for (int r = 0; r < 4; ++r) {
    ac0[r] = __builtin_amdgcn_exp2f(ac0[r]);
    ac1[r] = __builtin_amdgcn_exp2f(ac1[r]);
  }

  if (isq) {
    float* o = qp + (size_t)(gr0 + 4 * rw) * NH + hh * 128 + L;
    #pragma unroll
    for (int r = 0; r < 4; ++r) {
      o[(size_t)r * NH]      = ac0[r];
      o[(size_t)r * NH + 64] = ac1[r];
    }
  } else {
    /* transpose (h-lane, 4k) -> (k-lane, 4h) through padded LDS */
    __syncthreads();                         /* xs reads done */
    float* trs = xs;                         /* [128 h][17 pad] */
    *(float4*)&trs[(L     ) * 17 + 4 * rw] = make_float4(ac0[0], ac0[1], ac0[2], ac0[3]);
    *(float4*)&trs[(L + 64) * 17 + 4 * rw] = make_float4(ac1[0], ac1[1], ac1[2], ac1[3]);
    __syncthreads();
    const int kl = t & 15, jl2 = t >> 4;     /* jl2 0..15 */
    const int g0 = gr0 - NB * NQ;
    const int bb = g0 >> 10, kg0 = g0 & (NK - 1);
    #pragma unroll
    for (int it = 0; it < 2; ++it) {
      const int jl = jl2 + 16 * it;          /* 0..31 */
      float4 o4 = make_float4(trs[(4*jl+0)*17 + kl], trs[(4*jl+1)*17 + kl],
                              trs[(4*jl+2)*17 + kl], trs[(4*jl+3)*17 + kl]);
      ((float4*)kp)[((size_t)bb * 64 + hh * 32 + jl) * 1024 + kg0 + kl] = o4;
    }
  }
}

/* Scores kernel: grid (2 kh, 64 q4, 4 b) = 512 blocks, 1024 thr,
 * __launch_bounds__(1024,8).  Lane map: l = hs*16+kl; wave w = rh*8+kw.
 * Thread: k = kh*512 + (kw*16+kl)*4 + [0,4), rows {2rh,2rh+1}, j in
 * [hs*16, hs*16+16).  hs-butterfly via shfl_xor(16),(32).  el padded
 * stride-5 (R14 had 8-way write conflicts at stride-4).  FF_PAIRK =
 * R13-verified. */
__global__ __launch_bounds__(1024, 8) void ff_attn_s(
    const float* __restrict__ qp, const float* __restrict__ kp,
    const int* __restrict__ vlraw, const float* __restrict__ wvp,
    float* __restrict__ Eg, float* __restrict__ Sg)
{
  __shared__ float  qs[QROWS * NH];       /* Aq [row][h]            4 KB */
  __shared__ float4 wspp[NH / 2];         /* (-2w0,-2w1,-2(w0+w1),0) 2 KB */
  __shared__ float  el[512 * 5];          /* [k_local][5 pad] E    10 KB */
  __shared__ float  psum[32];             /* [wave][2 rows]               */

  const int t  = threadIdx.x;
  const int kh = blockIdx.x;              /* k half 0..1 */
  const int q4 = blockIdx.y;
  const int b  = blockIdx.z;

  qs[t] = qp[((size_t)b * NQ + q4 * QROWS) * NH + t];
  if (t < NH / 2) {
    float w0 = wvp[2 * t], w1 = wvp[2 * t + 1];
    wspp[t] = make_float4(-2.0f * w0, -2.0f * w1, -2.0f * (w0 + w1), 0.0f);
  }
  __syncthreads();

  int vls[4];
  ff_vldec(vlraw, vls);
  const int vl = vls[b];

  const int l  = t & 63, w = t >> 6;
  const int hs = l >> 4, kl = l & 15;     /* h-quarter in lane bits 4-5 */
  const int kw = w & 7,  rh = w >> 3;
  const int kk = kw * 16 + kl;            /* 0..127 */
  const int k0 = kh * 512 + kk * 4;       /* global k base */

  v2f acc0 = {0.f,0.f}, acc1 = {0.f,0.f}, acc2 = {0.f,0.f}, acc3 = {0.f,0.f};
  {
    const float4* kvp = (const float4*)kp + (size_t)b * 64 * 1024 + k0;
    const float* q0p = qs + (2 * rh) * NH;
    const float* q1p = qs + (2 * rh + 1) * NH;

    for (int jj = 0; jj < 16; ++jj) {
      const int j = hs * 16 + jj;
      const float4* kj = kvp + ((size_t)j << 10);
      float4 K0 = kj[0], K1 = kj[1], K2 = kj[2], K3 = kj[3];
      float4 A0 = *(const float4*)(q0p + 4 * j);
      float4 A1 = *(const float4*)(q1p + 4 * j);
      float4 wa = wspp[2 * j];
      float4 wb = wspp[2 * j + 1];
      v2f one; one.x = 1.0f; one.y = 1.0f;

#define FF_PAIRK(K4, ACC)                                                  \
      {                                                                    \
        v2f a, b2, D, N, w0v, w1v, rD;                                     \
        a.x  = A0.x * K4.x; a.y  = A1.x * K4.x;                            \
        b2.x = A0.y * K4.y; b2.y = A1.y * K4.y;                            \
        D = (one + a) * (one + b2);                                        \
        N.x = wa.z; N.y = wa.z;                                            \
        w0v.x = wa.x; w0v.y = wa.x;                                        \
        w1v.x = wa.y; w1v.y = wa.y;                                        \
        N += w0v * b2; N += w1v * a;                                       \
        rD.x = __builtin_amdgcn_rcpf(D.x);                                 \
        rD.y = __builtin_amdgcn_rcpf(D.y);                                 \
        ACC += N * rD;                                                     \
        a.x  = A0.z * K4.z; a.y  = A1.z * K4.z;                            \
        b2.x = A0.w * K4.w; b2.y = A1.w * K4.w;                            \
        D = (one + a) * (one + b2);                                        \
        N.x = wb.z; N.y = wb.z;                                            \
        w0v.x = wb.x; w0v.y = wb.x;                                        \
        w1v.x = wb.y; w1v.y = wb.y;                                        \
        N += w0v * b2; N += w1v * a;                                       \
        rD.x = __builtin_amdgcn_rcpf(D.x);                                 \
        rD.y = __builtin_amdgcn_rcpf(D.y);                                 \
        ACC += N * rD;                                                     \
      }
      FF_PAIRK(K0, acc0)
      FF_PAIRK(K1, acc1)
      FF_PAIRK(K2, acc2)
      FF_PAIRK(K3, acc3)
#undef FF_PAIRK
    }
  }

  /* combine h-quarters across lanes l^16, l^32 (butterfly) */
#define FF_RED(v)                                                          \
  v.x += __shfl_xor(v.x, 16); v.x += __shfl_xor(v.x, 32);                  \
  v.y += __shfl_xor(v.y, 16); v.y += __shfl_xor(v.y, 32);
  FF_RED(acc0) FF_RED(acc1) FF_RED(acc2) FF_RED(acc3)
#undef FF_RED

  /* E = exp2(score'), masked -> 0 */
  float ex0, ey0, ex1, ey1, ex2, ey2, ex3, ey3;
  {
    const bool m0 = (k0 + 0) < vl, m1 = (k0 + 1) < vl;
    const bool m2 = (k0 + 2) < vl, m3 = (k0 + 3) < vl;
    ex0 = m0 ? __builtin_amdgcn_exp2f(acc0.x * L2E) : 0.f;
    ey0 = m0 ? __builtin_amdgcn_exp2f(acc0.y * L2E) : 0.f;
    ex1 = m1 ? __builtin_amdgcn_exp2f(acc1.x * L2E) : 0.f;
    ey1 = m1 ? __builtin_amdgcn_exp2f(acc1.y * L2E) : 0.f;
    ex2 = m2 ? __builtin_amdgcn_exp2f(acc2.x * L2E) : 0.f;
    ey2 = m2 ? __builtin_amdgcn_exp2f(acc2.y * L2E) : 0.f;
    ex3 = m3 ? __builtin_amdgcn_exp2f(acc3.x * L2E) : 0.f;
    ey3 = m3 ? __builtin_amdgcn_exp2f(acc3.y * L2E) : 0.f;
  }

  /* hs==0 lanes: stage E into el (stride-5) + contribute to row sums */
  if (hs == 0) {
    const int klc = kk * 4;
    el[(klc + 0) * 5 + 2 * rh] = ex0; el[(klc + 0) * 5 + 2 * rh + 1] = ey0;
    el[(klc + 1) * 5 + 2 * rh] = ex1; el[(klc + 1) * 5 + 2 * rh + 1] = ey1;
    el[(klc + 2) * 5 + 2 * rh] = ex2; el[(klc + 2) * 5 + 2 * rh + 1] = ey2;
    el[(klc + 3) * 5 + 2 * rh] = ex3; el[(klc + 3) * 5 + 2 * rh + 1] = ey3;
  }
  {
    float sl = (hs == 0) ? ((ex0 + ex1) + (ex2 + ex3)) : 0.f;
    float sh = (hs == 0) ? ((ey0 + ey1) + (ey2 + ey3)) : 0.f;
    for (int o = 32; o; o >>= 1) { sl += __shfl_xor(sl, o); sh += __shfl_xor(sh, o); }
    if (l == 0) { psum[w * 2] = sl; psum[w * 2 + 1] = sh; }
  }
  __syncthreads();

  /* Eg write (float4 per k, coalesced) */
  if (t < 512) {
    const float* e = &el[t * 5];
    ((float4*)Eg)[((size_t)b * 64 + q4) * NK + kh * 512 + t]
        = make_float4(e[0], e[1], e[2], e[3]);
  }

  if (t < 4) {                            /* row r: waves rh=r>>1, comp r&1 */
    const int c = t & 1, base = (t >> 1) * 8;
    float S = 0.f;
    #pragma unroll
    for (int kw2 = 0; kw2 < 8; ++kw2) S += psum[(base + kw2) * 2 + c];
    Sg[(((size_t)b * 64 + q4) * 4 + t) * 2 + kh] = S;
  }
}

/* PV kernel: grid (8 c-tiles, 32 q-groups, 4 b) = 1024 blocks x 256 thr,
 * 16KB LDS.  8 q-rows/block (2 Eg float4 streams) -> values traffic /2.
 * Thread: cl=t&31 (c-pair), kq=t>>5 (128-k slice).  Sg summed over kh. */
__global__ __launch_bounds__(256) void ff_pv(
    const float* __restrict__ vals, const float* __restrict__ Eg,
    const float* __restrict__ Sg, const int* __restrict__ vlraw,
    float* __restrict__ out)
{
  __shared__ float part[8 * 8 * 64];      /* [kq][row][c-in-tile]  16 KB */
  const int t  = threadIdx.x;
  const int ct = blockIdx.x;              /* c-tile 0..7 */
  const int qg = blockIdx.y;              /* 8-row group 0..31 */
  const int b  = blockIdx.z;

  int vls[4];
  ff_vldec(vlraw, vls);
  const int vl = vls[b];

  const int cl = t & 31, kq = t >> 5;
  const int c  = ct * 64 + cl * 2;
  const int k0 = kq * 128;
  int klen = vl - k0; klen = klen < 0 ? 0 : (klen > 128 ? 128 : klen);

  const float*  vb  = vals + (size_t)b * NK * ND + (size_t)k0 * ND + c;
  const float4* epa = (const float4*)Eg + ((size_t)b * 64 + qg * 2    ) * NK + k0;
  const float4* epb = (const float4*)Eg + ((size_t)b * 64 + qg * 2 + 1) * NK + k0;

  v2f a0 = {0.f,0.f}, a1 = {0.f,0.f}, a2 = {0.f,0.f}, a3 = {0.f,0.f};
  v2f a4 = {0.f,0.f}, a5 = {0.f,0.f}, a6 = {0.f,0.f}, a7 = {0.f,0.f};
  #pragma unroll 4
  for (int k = 0; k < klen; ++k) {
    float4 Ea = epa[k];                   /* uniform -> s_load */
    float4 Eb = epb[k];
    v2f v = *(const v2f*)(vb + (size_t)k * ND);
    v2f e;
    e.x = Ea.x; e.y = Ea.x; a0 += e * v;
    e.x = Ea.y; e.y = Ea.y; a1 += e * v;
    e.x = Ea.z; e.y = Ea.z; a2 += e * v;
    e.x = Ea.w; e.y = Ea.w; a3 += e * v;
    e.x = Eb.x; e.y = Eb.x; a4 += e * v;
    e.x = Eb.y; e.y = Eb.y; a5 += e * v;
    e.x = Eb.z; e.y = Eb.z; a6 += e * v;
    e.x = Eb.w; e.y = Eb.w; a7 += e * v;
  }
  {
    float* pp = &part[(size_t)(kq * 8) * 64 + cl * 2];
    *(v2f*)(pp      ) = a0;
    *(v2f*)(pp + 64 ) = a1;
    *(v2f*)(pp + 128) = a2;
    *(v2f*)(pp + 192) = a3;
    *(v2f*)(pp + 256) = a4;
    *(v2f*)(pp + 320) = a5;
    *(v2f*)(pp + 384) = a6;
    *(v2f*)(pp + 448) = a7;
  }
  __syncthreads();
  {
    const int cc = t & 63;
    #pragma unroll
    for (int rr = 0; rr < 2; ++rr) {
      const int row = (t >> 6) * 2 + rr;  /* 0..7 */
      float s = 0.f;
      #pragma unroll
      for (int q = 0; q < 8; ++q) s += part[(size_t)(q * 8 + row) * 64 + cc];
      const int q4 = qg * 2 + (row >> 2), r = row & 3;
      const size_t sb = ((size_t)b * 64 + q4) * 4 + r;
      const float S = Sg[sb * 2] + Sg[sb * 2 + 1];
      out[((size_t)b * NQ + q4 * QROWS + r) * ND + ct * 64 + cc] = s / S;
    }
  }
}

/* Fallback attn (kp4 inputs, full K, in-kernel max-softmax) for small ws. */
__global__ __launch_bounds__(1024) void ff_attn(
    const float* __restrict__ qp, const float* __restrict__ kp,
    const float* __restrict__ vals, const int* __restrict__ vlraw,
    const float* __restrict__ wvp, float* __restrict__ out)
{
  __shared__ float qs[QROWS * NH];        /* [row][h] */
  __shared__ float ws[NH];
  __shared__ float st[NK * QROWS];
  __shared__ float pm[16], psm[16];
  __shared__ float part[4 * QROWS * ND];

  const int t  = threadIdx.x;
  const int q0 = blockIdx.x * QROWS;
  const int b  = blockIdx.y;

  {
    const float* qsrc = qp + ((size_t)b * NQ + q0) * NH;
    qs[t] = qsrc[t];
    if (t < NH) ws[t] = -2.0f * wvp[t];
  }
  __syncthreads();

  int vls[4];
  ff_vldec(vlraw, vls);
  const int vl = vls[b];

  float sc[4] = {0.f, 0.f, 0.f, 0.f};
  {
    const float4* kvp = (const float4*)kp + ((size_t)b * 64) * 1024 + t;
    for (int j = 0; j < 64; ++j) {
      float4 K4 = kvp[(size_t)j << 10];
      const float* wj = &ws[4 * j];
      #pragma unroll
      for (int r = 0; r < 4; ++r) {
        const float* qr = &qs[r * NH + 4 * j];
        sc[r] += wj[0] * __builtin_amdgcn_rcpf(1.0f + qr[0] * K4.x);
        sc[r] += wj[1] * __builtin_amdgcn_rcpf(1.0f + qr[1] * K4.y);
        sc[r] += wj[2] * __builtin_amdgcn_rcpf(1.0f + qr[2] * K4.z);
        sc[r] += wj[3] * __builtin_amdgcn_rcpf(1.0f + qr[3] * K4.w);
      }
    }
  }
  {
    const bool okm = (t < vl);
    *(float4*)&st[t * 4] = make_float4(okm ? sc[0] : -1e6f, okm ? sc[1] : -1e6f,
                                       okm ? sc[2] : -1e6f, okm ? sc[3] : -1e6f);
  }
  __syncthreads();

  {
    const int wid = t >> 6, lane = t & 63;
    const int row = wid >> 2, seg = wid & 3;
    const int kb = seg * 256 + lane;
    float v0 = st[(kb      ) * 4 + row];
    float v1 = st[(kb +  64) * 4 + row];
    float v2 = st[(kb + 128) * 4 + row];
    float v3 = st[(kb + 192) * 4 + row];
    float m = fmaxf(fmaxf(v0, v1), fmaxf(v2, v3));
    for (int o = 32; o; o >>= 1) m = fmaxf(m, __shfl_xor(m, o));
    if (lane == 0) pm[wid] = m;
    __syncthreads();
    m = fmaxf(fmaxf(pm[row*4+0], pm[row*4+1]), fmaxf(pm[row*4+2], pm[row*4+3]));
    float e0 = __builtin_amdgcn_exp2f((v0 - m) * L2E);
    float e1 = __builtin_amdgcn_exp2f((v1 - m) * L2E);
    float e2 = __builtin_amdgcn_exp2f((v2 - m) * L2E);
    float e3 = __builtin_amdgcn_exp2f((v3 - m) * L2E);
    float sm = e0 + e1 + e2 + e3;
    for (int o = 32; o; o >>= 1) sm += __shfl_xor(sm, o);
    if (lane == 0) psm[wid] = sm;
    __syncthreads();
    const float S = psm[row*4+0] + psm[row*4+1] + psm[row*4+2] + psm[row*4+3];
    const float rr = 1.0f / S;
    st[(kb      ) * 4 + row] = e0 * rr;
    st[(kb +  64) * 4 + row] = e1 * rr;
    st[(kb + 128) * 4 + row] = e2 * rr;
    st[(kb + 192) * 4 + row] = e3 * rr;
  }
  __syncthreads();

  {
    const int kq = t >> 8, c2 = (t & 255) * 2;
    const float* vb = vals + (size_t)b * NK * ND + c2;
    v2f o0 = {0.f,0.f}, o1 = {0.f,0.f}, o2 = {0.f,0.f}, o3 = {0.f,0.f};
    const int k0 = kq * 256;
    #pragma unroll 8
    for (int k = k0; k < k0 + 256; ++k) {
      v2f vv = *(const v2f*)(vb + (size_t)k * ND);
      float4 a = *(const float4*)&st[k * 4];
      v2f ax; ax.x = a.x; ax.y = a.x;
      v2f ay; ay.x = a.y; ay.y = a.y;
      v2f az; az.x = a.z; az.y = a.z;
      v2f aw; aw.x = a.w; aw.y = a.w;
      o0 += ax * vv; o1 += ay * vv; o2 += az * vv; o3 += aw * vv;
    }
    float* pp = &part[(size_t)kq * QROWS * ND + c2];
    *(v2f*)(pp         ) = o0;
    *(v2f*)(pp +     ND) = o1;
    *(v2f*)(pp + 2 * ND) = o2;
    *(v2f*)(pp + 3 * ND) = o3;
  }
  __syncthreads();
  {
    const int r = t >> 8, c2 = (t & 255) * 2;
    const float* pp = &part[(size_t)r * ND + c2];
    v2f s = {0.f, 0.f};
    #pragma unroll
    for (int kq = 0; kq < 4; ++kq) s += *(const v2f*)(pp + (size_t)kq * QROWS * ND);
    *(v2f*)(out + ((size_t)b * NQ + q0 + r) * ND + c2) = s;
  }
}

extern "C" void kernel_launch(void* const* d_in, const int* in_sizes, int n_in,
                              void* d_out, int out_size, void* d_ws, size_t ws_size,
                              hipStream_t stream) {
  const float* queries = (const float*)d_in[0];
  const float* keys    = (const float*)d_in[1];
  const float* values  = (const float*)d_in[2];
  const int*   vlens   = (const int*)d_in[3];
  const float* Wq      = (const float*)d_in[4];
  const float* Wk      = (const float*)d_in[5];
  const float* wv      = (const float*)d_in[6];
  float* out = (float*)d_out;               /* F32 OUTPUT */

  float* qp  = (float*)d_ws;                    /* 1 MB  */
  float* kp  = qp  + (size_t)NB * NQ * NH;      /* 4 MB (kp4 layout) */
  float* wtq = kp  + (size_t)NB * NH * NK;      /* 512 KB */
  float* wtk = wtq + (size_t)(ND / 4) * NH * 4; /* 512 KB */
  float* Eg  = wtk + (size_t)(ND / 4) * NH * 4; /* 4 MB (E float4/k) */
  float* Sg  = Eg  + (size_t)NB * 64 * NK * 4;  /* 8 KB (x2 kh) */
  const size_t need = ((size_t)(Sg - (float*)d_ws) + NB * 64 * 4 * 2) * sizeof(float);

  ff_wt  <<<dim3(128, 2), 256, 0, stream>>>(Wq, Wk, wtq, wtk);
  ff_proj<<<dim3((NB * (NQ + NK) / PJR) * 2), 256, 0, stream>>>(
      queries, keys, wtq, wtk, qp, kp);
  if (ws_size >= need) {
    ff_attn_s<<<dim3(2, NQ / QROWS, NB), 1024, 0, stream>>>(
        qp, kp, vlens, wv, Eg, Sg);
    ff_pv<<<dim3(8, NQ / (QROWS * 2), NB), 256, 0, stream>>>(
        values, Eg, Sg, vlens, out);
  } else {
    ff_attn<<<dim3(NQ / QROWS, NB), 1024, 0, stream>>>(
        qp, kp, values, vlens, wv, out);
  }
}

// Round 16
// 181.707 us; speedup vs baseline: 1.0117x; 1.0117x over previous
//
#include <hip/hip_runtime.h>
#include <stdint.h>

/* AdditiveAttention (B=4, Q=256, K=1024, D=512, H=256)
 * out[b,i,v] = sum_j softmax_j(sum_h tanh(q[b,i,h]+k[b,j,h])*wv[h]) * values[b,j,v],
 * masked to j < valid_lens[b].  OUTPUT IS FLOAT32 (R20 finding).
 *
 * R36: revert proj to the R14-proven version. R15's 2-h-tile proj (640
 * blocks) halved LDS instrs but ALSO halved parallelism -> occupancy 18%,
 * proj 49.7us, total regressed (proj is LATENCY-bound, scales with blocks —
 * same lesson as R5/R7; broadcast LDS reads are cheap, not 12cyc). Keep
 * R15's two good fixes: (a) attn_s el staged at stride-5 (kills R14's 3.38M
 * bank conflicts), (b) pv 8 q-rows/block (values traffic halved).
 * proj = R11/R14 exact: 1280 blocks (16 rows x 64-h tile), 5 blocks/CU,
 * per d4: 1 WT float4 + 4 broadcast LDS b128 + 16 FMA, kp4 via LDS
 * transpose. */

#define NB 4
#define NQ 256
#define NK 1024
#define ND 512
#define NH 256
#define QROWS 4
#define PJR 16
#define PJH 64

#define C2L2E 2.8853900817779268f   /* 2*log2(e) */
#define L2E   1.4426950408889634f   /* log2(e)   */

typedef float v2f __attribute__((ext_vector_type(2)));

/* 8-class valid_lens decode: {i32,i64,f32,f64,i16,f16,bf16,fallback}. */
__device__ void ff_vldec(const int* p, int* v) {
  bool ok = true;
  for (int i = 0; i < 4; ++i) { int x = p[i]; if (x < 1 || x > NK) ok = false; }
  if (ok) { for (int i = 0; i < 4; ++i) v[i] = p[i]; return; }
  ok = true;
  for (int i = 0; i < 4; ++i) {
    if (p[2 * i + 1] != 0) ok = false;
    int x = p[2 * i]; if (x < 1 || x > NK) ok = false;
  }
  if (ok) { for (int i = 0; i < 4; ++i) v[i] = p[2 * i]; return; }
  ok = true;
  for (int i = 0; i < 4; ++i) {
    union { int i; float f; } u; u.i = p[i];
    if (!(u.f >= 1.0f && u.f <= 1024.0f && u.f == floorf(u.f))) ok = false;
  }
  if (ok) {
    for (int i = 0; i < 4; ++i) { union { int i; float f; } u; u.i = p[i]; v[i] = (int)u.f; }
    return;
  }
  ok = true;
  for (int i = 0; i < 4; ++i) {
    union { long long l; double d; } u;
    u.l = ((long long)p[2 * i + 1] << 32) | (unsigned int)p[2 * i];
    if (!(u.d >= 1.0 && u.d <= 1024.0 && u.d == floor(u.d))) ok = false;
  }
  if (ok) {
    for (int i = 0; i < 4; ++i) {
      union { long long l; double d; } u;
      u.l = ((long long)p[2 * i + 1] << 32) | (unsigned int)p[2 * i];
      v[i] = (int)u.d;
    }
    return;
  }
  const uint16_t* hh = (const uint16_t*)p;
  const short*    s  = (const short*)p;
  ok = true;
  for (int i = 0; i < 4; ++i) { int x = s[i]; if (x < 1 || x > NK) ok = false; }
  if (ok) { for (int i = 0; i < 4; ++i) v[i] = s[i]; return; }
  ok = true;
  for (int i = 0; i < 4; ++i) {
    union { uint16_t u; _Float16 h; } u; u.u = hh[i];
    float f = (float)u.h;
    if (!(f >= 1.0f && f <= 1024.0f && f == floorf(f))) ok = false;
  }
  if (ok) {
    for (int i = 0; i < 4; ++i) {
      union { uint16_t u; _Float16 h; } u; u.u = hh[i];
      v[i] = (int)(float)u.h;
    }
    return;
  }
  ok = true;
  for (int i = 0; i < 4; ++i) {
    union { uint32_t u; float f; } u; u.u = ((uint32_t)hh[i]) << 16;
    if (!(u.f >= 1.0f && u.f <= 1028.0f)) ok = false;
  }
  if (ok) {
    for (int i = 0; i < 4; ++i) {
      union { uint32_t u; float f; } u; u.u = ((uint32_t)hh[i]) << 16;
      int x = (int)(u.f + 0.5f); if (x > NK) x = NK; v[i] = x;
    }
    return;
  }
  for (int i = 0; i < 4; ++i) v[i] = NK;  /* fail-safe: unmasked */
}

/* Transpose W[h][d] -> WT float4 #(d4*NH+h) = C2L2E * W[h][4d4..4d4+3]. */
__global__ __launch_bounds__(256) void ff_wt(
    const float* __restrict__ Wq, const float* __restrict__ Wk,
    float* __restrict__ WTq, float* __restrict__ WTk)
{
  const int idx = blockIdx.x * 256 + threadIdx.x;   /* 0..32767 */
  const int d4 = idx & 127, h = idx >> 7;
  const float* src = blockIdx.y ? Wk : Wq;
  float*       dst = blockIdx.y ? WTk : WTq;
  float4 w = *(const float4*)(src + (size_t)h * ND + d4 * 4);
  w.x *= C2L2E; w.y *= C2L2E; w.z *= C2L2E; w.w *= C2L2E;
  *(float4*)(dst + ((size_t)d4 * NH + h) * 4) = w;
}

/* Projection (R11/R14 exact, proven): grid = 320 row-groups x 4 h-tiles =
 * 1280 blocks, 256 thr, 32KB LDS -> 5 blocks/CU. Wave rw: rows 4rw..4rw+3
 * (broadcast ds_read); lane owns h = h0 + (t&63) (WT coalesced). Per d4:
 * 1 vmem f4 + 4 ds b128 + 16 FMA. Outputs Aq=2^{q'} (qp [r][h]) and
 * Ak=2^{k'} interleaved kp4[b][j][k] via 4KB LDS transpose. */
__global__ __launch_bounds__(256) void ff_proj(
    const float* __restrict__ q_in, const float* __restrict__ k_in,
    const float* __restrict__ WTq, const float* __restrict__ WTk,
    float* __restrict__ qp, float* __restrict__ kp)
{
  __shared__ float xs[PJR * ND];                 /* 32 KB */
  const int t  = threadIdx.x;
  const int rg = blockIdx.x >> 2;                /* 0..319 */
  const int h0 = (blockIdx.x & 3) * PJH;
  const int gr0 = rg * PJR;
  const bool isq = gr0 < NB * NQ;
  const float* xin = isq ? (q_in + (size_t)gr0 * ND)
                         : (k_in + (size_t)(gr0 - NB * NQ) * ND);
  const float4* wt4 = (const float4*)(isq ? WTq : WTk);

  #pragma unroll
  for (int i = 0; i < 8; ++i)
    ((float4*)xs)[t + 256 * i] = ((const float4*)xin)[t + 256 * i];
  __syncthreads();

  const int L  = t & 63;
  const int rw = t >> 6;
  float a0 = 0.f, a1 = 0.f, a2 = 0.f, a3 = 0.f;
  const float4* xr = (const float4*)xs + (size_t)(4 * rw) * 128;

  #pragma unroll 4
  for (int d4 = 0; d4 < ND / 4; ++d4) {
    float4 w  = wt4[(size_t)d4 * NH + h0 + L];
    float4 x0 = xr[d4];
    float4 x1 = xr[128 + d4];
    float4 x2 = xr[256 + d4];
    float4 x3 = xr[384 + d4];
    a0 += w.x*x0.x + w.y*x0.y + w.z*x0.z + w.w*x0.w;
    a1 += w.x*x1.x + w.y*x1.y + w.z*x1.z + w.w*x1.w;
    a2 += w.x*x2.x + w.y*x2.y + w.z*x2.z + w.w*x2.w;
    a3 += w.x*x3.x + w.y*x3.y + w.z*x3.z + w.w*x3.w;
  }
  a0 = __builtin_amdgcn_exp2f(a0);
  a1 = __builtin_amdgcn_exp2f(a1);
  a2 = __builtin_amdgcn_exp2f(a2);
  a3 = __builtin_amdgcn_exp2f(a3);

  if (isq) {
    const int h = h0 + L;
    float* o = qp + (size_t)(gr0 + 4 * rw) * NH + h;
    o[0] = a0; o[NH] = a1; o[2 * NH] = a2; o[3 * NH] = a3;
  } else {
    /* transpose (h-lane, 4k) -> (k-lane, 4h) through LDS, write kp4 */
    __syncthreads();                         /* xs reads done */
    float* trs = xs;                         /* [64 h][16 k] */
    *(float4*)&trs[L * 16 + 4 * rw] = make_float4(a0, a1, a2, a3);
    __syncthreads();
    const int kl = t & 15, jl = t >> 4;      /* jl 0..15 */
    const int g0 = gr0 - NB * NQ;
    const int bb = g0 >> 10, kg0 = g0 & (NK - 1);
    const int j0 = (blockIdx.x & 3) * 16;
    float4 o4 = make_float4(trs[(4*jl+0)*16 + kl], trs[(4*jl+1)*16 + kl],
                            trs[(4*jl+2)*16 + kl], trs[(4*jl+3)*16 + kl]);
    ((float4*)kp)[((size_t)bb * 64 + j0 + jl) * 1024 + kg0 + kl] = o4;
  }
}

/* Scores kernel: grid (2 kh, 64 q4, 4 b) = 512 blocks, 1024 thr,
 * __launch_bounds__(1024,8).  Lane map: l = hs*16+kl; wave w = rh*8+kw.
 * Thread: k = kh*512 + (kw*16+kl)*4 + [0,4), rows {2rh,2rh+1}, j in
 * [hs*16, hs*16+16).  hs-butterfly via shfl_xor(16),(32).  el padded
 * stride-5 (R15 fix: R14's stride-4 had 8-way write conflicts).
 * FF_PAIRK = R13-verified. */
__global__ __launch_bounds__(1024, 8) void ff_attn_s(
    const float* __restrict__ qp, const float* __restrict__ kp,
    const int* __restrict__ vlraw, const float* __restrict__ wvp,
    float* __restrict__ Eg, float* __restrict__ Sg)
{
  __shared__ float  qs[QROWS * NH];       /* Aq [row][h]            4 KB */
  __shared__ float4 wspp[NH / 2];         /* (-2w0,-2w1,-2(w0+w1),0) 2 KB */
  __shared__ float  el[512 * 5];          /* [k_local][5 pad] E    10 KB */
  __shared__ float  psum[32];             /* [wave][2 rows]               */

  const int t  = threadIdx.x;
  const int kh = blockIdx.x;              /* k half 0..1 */
  const int q4 = blockIdx.y;
  const int b  = blockIdx.z;

  qs[t] = qp[((size_t)b * NQ + q4 * QROWS) * NH + t];
  if (t < NH / 2) {
    float w0 = wvp[2 * t], w1 = wvp[2 * t + 1];
    wspp[t] = make_float4(-2.0f * w0, -2.0f * w1, -2.0f * (w0 + w1), 0.0f);
  }
  __syncthreads();

  int vls[4];
  ff_vldec(vlraw, vls);
  const int vl = vls[b];

  const int l  = t & 63, w = t >> 6;
  const int hs = l >> 4, kl = l & 15;     /* h-quarter in lane bits 4-5 */
  const int kw = w & 7,  rh = w >> 3;
  const int kk = kw * 16 + kl;            /* 0..127 */
  const int k0 = kh * 512 + kk * 4;       /* global k base */

  v2f acc0 = {0.f,0.f}, acc1 = {0.f,0.f}, acc2 = {0.f,0.f}, acc3 = {0.f,0.f};
  {
    const float4* kvp = (const float4*)kp + (size_t)b * 64 * 1024 + k0;
    const float* q0p = qs + (2 * rh) * NH;
    const float* q1p = qs + (2 * rh + 1) * NH;

    for (int jj = 0; jj < 16; ++jj) {
      const int j = hs * 16 + jj;
      const float4* kj = kvp + ((size_t)j << 10);
      float4 K0 = kj[0], K1 = kj[1], K2 = kj[2], K3 = kj[3];
      float4 A0 = *(const float4*)(q0p + 4 * j);
      float4 A1 = *(const float4*)(q1p + 4 * j);
      float4 wa = wspp[2 * j];
      float4 wb = wspp[2 * j + 1];
      v2f one; one.x = 1.0f; one.y = 1.0f;

#define FF_PAIRK(K4, ACC)                                                  \
      {                                                                    \
        v2f a, b2, D, N, w0v, w1v, rD;                                     \
        a.x  = A0.x * K4.x; a.y  = A1.x * K4.x;                            \
        b2.x = A0.y * K4.y; b2.y = A1.y * K4.y;                            \
        D = (one + a) * (one + b2);                                        \
        N.x = wa.z; N.y = wa.z;                                            \
        w0v.x = wa.x; w0v.y = wa.x;                                        \
        w1v.x = wa.y; w1v.y = wa.y;                                        \
        N += w0v * b2; N += w1v * a;                                       \
        rD.x = __builtin_amdgcn_rcpf(D.x);                                 \
        rD.y = __builtin_amdgcn_rcpf(D.y);                                 \
        ACC += N * rD;                                                     \
        a.x  = A0.z * K4.z; a.y  = A1.z * K4.z;                            \
        b2.x = A0.w * K4.w; b2.y = A1.w * K4.w;                            \
        D = (one + a) * (one + b2);                                        \
        N.x = wb.z; N.y = wb.z;                                            \
        w0v.x = wb.x; w0v.y = wb.x;                                        \
        w1v.x = wb.y; w1v.y = wb.y;                                        \
        N += w0v * b2; N += w1v * a;                                       \
        rD.x = __builtin_amdgcn_rcpf(D.x);                                 \
        rD.y = __builtin_amdgcn_rcpf(D.y);                                 \
        ACC += N * rD;                                                     \
      }
      FF_PAIRK(K0, acc0)
      FF_PAIRK(K1, acc1)
      FF_PAIRK(K2, acc2)
      FF_PAIRK(K3, acc3)
#undef FF_PAIRK
    }
  }

  /* combine h-quarters across lanes l^16, l^32 (butterfly) */
#define FF_RED(v)                                                          \
  v.x += __shfl_xor(v.x, 16); v.x += __shfl_xor(v.x, 32);                  \
  v.y += __shfl_xor(v.y, 16); v.y += __shfl_xor(v.y, 32);
  FF_RED(acc0) FF_RED(acc1) FF_RED(acc2) FF_RED(acc3)
#undef FF_RED

  /* E = exp2(score'), masked -> 0 */
  float ex0, ey0, ex1, ey1, ex2, ey2, ex3, ey3;
  {
    const bool m0 = (k0 + 0) < vl, m1 = (k0 + 1) < vl;
    const bool m2 = (k0 + 2) < vl, m3 = (k0 + 3) < vl;
    ex0 = m0 ? __builtin_amdgcn_exp2f(acc0.x * L2E) : 0.f;
    ey0 = m0 ? __builtin_amdgcn_exp2f(acc0.y * L2E) : 0.f;
    ex1 = m1 ? __builtin_amdgcn_exp2f(acc1.x * L2E) : 0.f;
    ey1 = m1 ? __builtin_amdgcn_exp2f(acc1.y * L2E) : 0.f;
    ex2 = m2 ? __builtin_amdgcn_exp2f(acc2.x * L2E) : 0.f;
    ey2 = m2 ? __builtin_amdgcn_exp2f(acc2.y * L2E) : 0.f;
    ex3 = m3 ? __builtin_amdgcn_exp2f(acc3.x * L2E) : 0.f;
    ey3 = m3 ? __builtin_amdgcn_exp2f(acc3.y * L2E) : 0.f;
  }

  /* hs==0 lanes: stage E into el (stride-5) + contribute to row sums */
  if (hs == 0) {
    const int klc = kk * 4;
    el[(klc + 0) * 5 + 2 * rh] = ex0; el[(klc + 0) * 5 + 2 * rh + 1] = ey0;
    el[(klc + 1) * 5 + 2 * rh] = ex1; el[(klc + 1) * 5 + 2 * rh + 1] = ey1;
    el[(klc + 2) * 5 + 2 * rh] = ex2; el[(klc + 2) * 5 + 2 * rh + 1] = ey2;
    el[(klc + 3) * 5 + 2 * rh] = ex3; el[(klc + 3) * 5 + 2 * rh + 1] = ey3;
  }
  {
    float sl = (hs == 0) ? ((ex0 + ex1) + (ex2 + ex3)) : 0.f;
    float sh = (hs == 0) ? ((ey0 + ey1) + (ey2 + ey3)) : 0.f;
    for (int o = 32; o; o >>= 1) { sl += __shfl_xor(sl, o); sh += __shfl_xor(sh, o); }
    if (l == 0) { psum[w * 2] = sl; psum[w * 2 + 1] = sh; }
  }
  __syncthreads();

  /* Eg write (float4 per k, coalesced) */
  if (t < 512) {
    const float* e = &el[t * 5];
    ((float4*)Eg)[((size_t)b * 64 + q4) * NK + kh * 512 + t]
        = make_float4(e[0], e[1], e[2], e[3]);
  }

  if (t < 4) {                            /* row r: waves rh=r>>1, comp r&1 */
    const int c = t & 1, base = (t >> 1) * 8;
    float S = 0.f;
    #pragma unroll
    for (int kw2 = 0; kw2 < 8; ++kw2) S += psum[(base + kw2) * 2 + c];
    Sg[(((size_t)b * 64 + q4) * 4 + t) * 2 + kh] = S;
  }
}

/* PV kernel: grid (8 c-tiles, 32 q-groups, 4 b) = 1024 blocks x 256 thr,
 * 16KB LDS.  8 q-rows/block (2 Eg float4 streams) -> values traffic /2.
 * Thread: cl=t&31 (c-pair), kq=t>>5 (128-k slice).  Sg summed over kh. */
__global__ __launch_bounds__(256) void ff_pv(
    const float* __restrict__ vals, const float* __restrict__ Eg,
    const float* __restrict__ Sg, const int* __restrict__ vlraw,
    float* __restrict__ out)
{
  __shared__ float part[8 * 8 * 64];      /* [kq][row][c-in-tile]  16 KB */
  const int t  = threadIdx.x;
  const int ct = blockIdx.x;              /* c-tile 0..7 */
  const int qg = blockIdx.y;              /* 8-row group 0..31 */
  const int b  = blockIdx.z;

  int vls[4];
  ff_vldec(vlraw, vls);
  const int vl = vls[b];

  const int cl = t & 31, kq = t >> 5;
  const int c  = ct * 64 + cl * 2;
  const int k0 = kq * 128;
  int klen = vl - k0; klen = klen < 0 ? 0 : (klen > 128 ? 128 : klen);

  const float*  vb  = vals + (size_t)b * NK * ND + (size_t)k0 * ND + c;
  const float4* epa = (const float4*)Eg + ((size_t)b * 64 + qg * 2    ) * NK + k0;
  const float4* epb = (const float4*)Eg + ((size_t)b * 64 + qg * 2 + 1) * NK + k0;

  v2f a0 = {0.f,0.f}, a1 = {0.f,0.f}, a2 = {0.f,0.f}, a3 = {0.f,0.f};
  v2f a4 = {0.f,0.f}, a5 = {0.f,0.f}, a6 = {0.f,0.f}, a7 = {0.f,0.f};
  #pragma unroll 4
  for (int k = 0; k < klen; ++k) {
    float4 Ea = epa[k];                   /* uniform -> s_load */
    float4 Eb = epb[k];
    v2f v = *(const v2f*)(vb + (size_t)k * ND);
    v2f e;
    e.x = Ea.x; e.y = Ea.x; a0 += e * v;
    e.x = Ea.y; e.y = Ea.y; a1 += e * v;
    e.x = Ea.z; e.y = Ea.z; a2 += e * v;
    e.x = Ea.w; e.y = Ea.w; a3 += e * v;
    e.x = Eb.x; e.y = Eb.x; a4 += e * v;
    e.x = Eb.y; e.y = Eb.y; a5 += e * v;
    e.x = Eb.z; e.y = Eb.z; a6 += e * v;
    e.x = Eb.w; e.y = Eb.w; a7 += e * v;
  }
  {
    float* pp = &part[(size_t)(kq * 8) * 64 + cl * 2];
    *(v2f*)(pp      ) = a0;
    *(v2f*)(pp + 64 ) = a1;
    *(v2f*)(pp + 128) = a2;
    *(v2f*)(pp + 192) = a3;
    *(v2f*)(pp + 256) = a4;
    *(v2f*)(pp + 320) = a5;
    *(v2f*)(pp + 384) = a6;
    *(v2f*)(pp + 448) = a7;
  }
  __syncthreads();
  {
    const int cc = t & 63;
    #pragma unroll
    for (int rr = 0; rr < 2; ++rr) {
      const int row = (t >> 6) * 2 + rr;  /* 0..7 */
      float s = 0.f;
      #pragma unroll
      for (int q = 0; q < 8; ++q) s += part[(size_t)(q * 8 + row) * 64 + cc];
      const int q4 = qg * 2 + (row >> 2), r = row & 3;
      const size_t sb = ((size_t)b * 64 + q4) * 4 + r;
      const float S = Sg[sb * 2] + Sg[sb * 2 + 1];
      out[((size_t)b * NQ + q4 * QROWS + r) * ND + ct * 64 + cc] = s / S;
    }
  }
}

/* Fallback attn (kp4 inputs, full K, in-kernel max-softmax) for small ws. */
__global__ __launch_bounds__(1024) void ff_attn(
    const float* __restrict__ qp, const float* __restrict__ kp,
    const float* __restrict__ vals, const int* __restrict__ vlraw,
    const float* __restrict__ wvp, float* __restrict__ out)
{
  __shared__ float qs[QROWS * NH];        /* [row][h] */
  __shared__ float ws[NH];
  __shared__ float st[NK * QROWS];
  __shared__ float pm[16], psm[16];
  __shared__ float part[4 * QROWS * ND];

  const int t  = threadIdx.x;
  const int q0 = blockIdx.x * QROWS;
  const int b  = blockIdx.y;

  {
    const float* qsrc = qp + ((size_t)b * NQ + q0) * NH;
    qs[t] = qsrc[t];
    if (t < NH) ws[t] = -2.0f * wvp[t];
  }
  __syncthreads();

  int vls[4];
  ff_vldec(vlraw, vls);
  const int vl = vls[b];

  float sc[4] = {0.f, 0.f, 0.f, 0.f};
  {
    const float4* kvp = (const float4*)kp + ((size_t)b * 64) * 1024 + t;
    for (int j = 0; j < 64; ++j) {
      float4 K4 = kvp[(size_t)j << 10];
      const float* wj = &ws[4 * j];
      #pragma unroll
      for (int r = 0; r < 4; ++r) {
        const float* qr = &qs[r * NH + 4 * j];
        sc[r] += wj[0] * __builtin_amdgcn_rcpf(1.0f + qr[0] * K4.x);
        sc[r] += wj[1] * __builtin_amdgcn_rcpf(1.0f + qr[1] * K4.y);
        sc[r] += wj[2] * __builtin_amdgcn_rcpf(1.0f + qr[2] * K4.z);
        sc[r] += wj[3] * __builtin_amdgcn_rcpf(1.0f + qr[3] * K4.w);
      }
    }
  }
  {
    const bool okm = (t < vl);
    *(float4*)&st[t * 4] = make_float4(okm ? sc[0] : -1e6f, okm ? sc[1] : -1e6f,
                                       okm ? sc[2] : -1e6f, okm ? sc[3] : -1e6f);
  }
  __syncthreads();

  {
    const int wid = t >> 6, lane = t & 63;
    const int row = wid >> 2, seg = wid & 3;
    const int kb = seg * 256 + lane;
    float v0 = st[(kb      ) * 4 + row];
    float v1 = st[(kb +  64) * 4 + row];
    float v2 = st[(kb + 128) * 4 + row];
    float v3 = st[(kb + 192) * 4 + row];
    float m = fmaxf(fmaxf(v0, v1), fmaxf(v2, v3));
    for (int o = 32; o; o >>= 1) m = fmaxf(m, __shfl_xor(m, o));
    if (lane == 0) pm[wid] = m;
    __syncthreads();
    m = fmaxf(fmaxf(pm[row*4+0], pm[row*4+1]), fmaxf(pm[row*4+2], pm[row*4+3]));
    float e0 = __builtin_amdgcn_exp2f((v0 - m) * L2E);
    float e1 = __builtin_amdgcn_exp2f((v1 - m) * L2E);
    float e2 = __builtin_amdgcn_exp2f((v2 - m) * L2E);
    float e3 = __builtin_amdgcn_exp2f((v3 - m) * L2E);
    float sm = e0 + e1 + e2 + e3;
    for (int o = 32; o; o >>= 1) sm += __shfl_xor(sm, o);
    if (lane == 0) psm[wid] = sm;
    __syncthreads();
    const float S = psm[row*4+0] + psm[row*4+1] + psm[row*4+2] + psm[row*4+3];
    const float rr = 1.0f / S;
    st[(kb      ) * 4 + row] = e0 * rr;
    st[(kb +  64) * 4 + row] = e1 * rr;
    st[(kb + 128) * 4 + row] = e2 * rr;
    st[(kb + 192) * 4 + row] = e3 * rr;
  }
  __syncthreads();

  {
    const int kq = t >> 8, c2 = (t & 255) * 2;
    const float* vb = vals + (size_t)b * NK * ND + c2;
    v2f o0 = {0.f,0.f}, o1 = {0.f,0.f}, o2 = {0.f,0.f}, o3 = {0.f,0.f};
    const int k0 = kq * 256;
    #pragma unroll 8
    for (int k = k0; k < k0 + 256; ++k) {
      v2f vv = *(const v2f*)(vb + (size_t)k * ND);
      float4 a = *(const float4*)&st[k * 4];
      v2f ax; ax.x = a.x; ax.y = a.x;
      v2f ay; ay.x = a.y; ay.y = a.y;
      v2f az; az.x = a.z; az.y = a.z;
      v2f aw; aw.x = a.w; aw.y = a.w;
      o0 += ax * vv; o1 += ay * vv; o2 += az * vv; o3 += aw * vv;
    }
    float* pp = &part[(size_t)kq * QROWS * ND + c2];
    *(v2f*)(pp         ) = o0;
    *(v2f*)(pp +     ND) = o1;
    *(v2f*)(pp + 2 * ND) = o2;
    *(v2f*)(pp + 3 * ND) = o3;
  }
  __syncthreads();
  {
    const int r = t >> 8, c2 = (t & 255) * 2;
    const float* pp = &part[(size_t)r * ND + c2];
    v2f s = {0.f, 0.f};
    #pragma unroll
    for (int kq = 0; kq < 4; ++kq) s += *(const v2f*)(pp + (size_t)kq * QROWS * ND);
    *(v2f*)(out + ((size_t)b * NQ + q0 + r) * ND + c2) = s;
  }
}

extern "C" void kernel_launch(void* const* d_in, const int* in_sizes, int n_in,
                              void* d_out, int out_size, void* d_ws, size_t ws_size,
                              hipStream_t stream) {
  const float* queries = (const float*)d_in[0];
  const float* keys    = (const float*)d_in[1];
  const float* values  = (const float*)d_in[2];
  const int*   vlens   = (const int*)d_in[3];
  const float* Wq      = (const float*)d_in[4];
  const float* Wk      = (const float*)d_in[5];
  const float* wv      = (const float*)d_in[6];
  float* out = (float*)d_out;               /* F32 OUTPUT */

  float* qp  = (float*)d_ws;                    /* 1 MB  */
  float* kp  = qp  + (size_t)NB * NQ * NH;      /* 4 MB (kp4 layout) */
  float* wtq = kp  + (size_t)NB * NH * NK;      /* 512 KB */
  float* wtk = wtq + (size_t)(ND / 4) * NH * 4; /* 512 KB */
  float* Eg  = wtk + (size_t)(ND / 4) * NH * 4; /* 4 MB (E float4/k) */
  float* Sg  = Eg  + (size_t)NB * 64 * NK * 4;  /* 8 KB (x2 kh) */
  const size_t need = ((size_t)(Sg - (float*)d_ws) + NB * 64 * 4 * 2) * sizeof(float);

  ff_wt  <<<dim3(128, 2), 256, 0, stream>>>(Wq, Wk, wtq, wtk);
  ff_proj<<<dim3((NB * (NQ + NK) / PJR) * (NH / PJH)), 256, 0, stream>>>(
      queries, keys, wtq, wtk, qp, kp);
  if (ws_size >= need) {
    ff_attn_s<<<dim3(2, NQ / QROWS, NB), 1024, 0, stream>>>(
        qp, kp, vlens, wv, Eg, Sg);
    ff_pv<<<dim3(8, NQ / (QROWS * 2), NB), 256, 0, stream>>>(
        values, Eg, Sg, vlens, out);
  } else {
    ff_attn<<<dim3(NQ / QROWS, NB), 1024, 0, stream>>>(
        qp, kp, values, vlens, wv, out);
  }
}